// Round 9
// baseline (144.823 us; speedup 1.0000x reference)
//
#include <hip/hip_runtime.h>

// SNN forward — R13: R12 minus gate-2/smx/colmax-scan; cheap global-max gate.
//
// R12 audit: the per-wave W2 column-max scan (32 strided scalar loads +
// 31-deep dependent fmax chain + smx LDS round-trip + divergent gate-2
// S-loops) exists only to serve gate-2 -- which filters rows gate-1 already
// cut to ~0.7%. With the cooperative dense path costing ~40 uniform ops per
// surviving row, gate-2's infrastructure costs more than it saves.
//
// R13:
//  - mxmax = max over ALL 1024 W2 entries (same value as max_i colmax[i]):
//    4 coalesced v4f loads/lane + 15 fmax + 6-step shuffle tree. No LDS,
//    no serial 32-chain, no strided loads.
//  - gate-1 unchanged: popc(m)*mxmax < 1.998 -> provably no layer-2 spike
//    (fp sum err <= 31*2^-24*Sum|terms| ~ 4e-5 << margin). Kills ~99.3%.
//  - gate-1 survivors (~0.9 rows/wave) go straight to the R11/R12-verified
//    cooperative dense path; non-spiking rows die at the m2==0 ballot.
//    Removing a filter in FRONT of an exact path cannot change outputs.
//  - layer-1 packed v2f (R6/R7/R12-verified), early zero-burst (R12),
//    wave-private LDS x-stage (R8-R12), no barriers anywhere.
//
// Exactness: absmax 0.0 preserved -- every computational form below is
// byte-identical to a previously-verified round (R11/R12 paths), and the
// only removed elements are pure filters.

typedef float v4f __attribute__((ext_vector_type(4)));
typedef float v2f __attribute__((ext_vector_type(2)));

#define TPB 256
#define RPL 2                  // rows per lane
#define TROWS (64 * RPL)       // 128 rows per wave
#define RPB (TPB * RPL)        // 512 rows per block

__global__ __launch_bounds__(TPB) void snn_one(
    const float* __restrict__ x,
    const float* __restrict__ W1,   // [32,5]
    const float* __restrict__ W2,   // [32,32]
    const float* __restrict__ W3,   // [16,32]
    const float* __restrict__ W4,   // [10,16]
    float* __restrict__ out,        // [B,10]
    int B)
{
    __shared__ __align__(16) float xsh[4][TROWS * 5];   // 10KB: wave-private x

    const int t = threadIdx.x;
    const int wv = t >> 6, lane = t & 63;
    float* sb = xsh[wv];
    const long wt0 = (long)blockIdx.x * RPB + (long)wv * TROWS;
    if (wt0 >= B) return;

    const bool full = (wt0 + TROWS <= B);

    // ---- issue this wave's x loads FIRST ----
    v4f g0, g1, g2;
    if (full) {
        const v4f* xg = (const v4f*)(x + wt0 * 5);
        g0 = xg[lane];
        g1 = xg[64 + lane];
        if (lane < 32) g2 = xg[128 + lane];   // 160 v4f total
    }

    // ---- mxmax loads: 4 coalesced v4f/lane covering all 1024 W2 floats ----
    v4f wm0, wm1, wm2, wm3;
    {
        const v4f* w2g = (const v4f*)W2;
        wm0 = w2g[lane];
        wm1 = w2g[64 + lane];
        wm2 = w2g[128 + lane];
        wm3 = w2g[192 + lane];
    }

    // ---- EARLY coalesced zero-burst: drain overlaps compute below ----
    if (full) {
        v4f z = {0.0f, 0.0f, 0.0f, 0.0f};
        v4f* og = (v4f*)(out + wt0 * 10);
#pragma unroll
        for (int e = 0; e < 5; ++e) og[e * 64 + lane] = z;
    }

    // ---- mxmax reduce: 15 fmax + 6-step shuffle tree (wave-uniform) ----
    float mxmax;
    {
        float a = fmaxf(fmaxf(wm0.x, wm0.y), fmaxf(wm0.z, wm0.w));
        float b = fmaxf(fmaxf(wm1.x, wm1.y), fmaxf(wm1.z, wm1.w));
        float c = fmaxf(fmaxf(wm2.x, wm2.y), fmaxf(wm2.z, wm2.w));
        float d = fmaxf(fmaxf(wm3.x, wm3.y), fmaxf(wm3.z, wm3.w));
        mxmax = fmaxf(fmaxf(a, b), fmaxf(c, d));
#pragma unroll
        for (int off = 32; off; off >>= 1)
            mxmax = fmaxf(mxmax, __shfl_xor(mxmax, off));
    }

    if (full) {
        // ---- stage x -> wave-private LDS, read back own 2 rows ----
        v4f* s4 = (v4f*)sb;
        s4[lane] = g0;
        s4[64 + lane] = g1;
        if (lane < 32) s4[128 + lane] = g2;

        v2f xp[5];
        {
            const v2f* sx = (const v2f*)(sb + lane * 10);
#pragma unroll
            for (int e = 0; e < 5; ++e) xp[e] = sx[e];
        }
        const float* xf = (const float*)xp;

        // ---- layer 1: packed v2f, j2-outer (R6/R7/R12-verified form);
        //      W1 pair-vectors from uniform scalar loads (SALU/K$) ----
        unsigned m[RPL] = {0u, 0u};
#pragma unroll
        for (int j2 = 0; j2 < 16; ++j2) {
            const float* wA = W1 + (2 * j2) * 5;
            const float* wB = W1 + (2 * j2 + 1) * 5;
            const v2f w0 = {wA[0], wB[0]};
            const v2f w1 = {wA[1], wB[1]};
            const v2f w2 = {wA[2], wB[2]};
            const v2f w3 = {wA[3], wB[3]};
            const v2f w4 = {wA[4], wB[4]};
#pragma unroll
            for (int c = 0; c < RPL; ++c) {
                v2f h = xf[c * 5 + 0] * w0;   // exact per-neuron chain order
                h += xf[c * 5 + 1] * w1;
                h += xf[c * 5 + 2] * w2;
                h += xf[c * 5 + 3] * w3;
                h += xf[c * 5 + 4] * w4;
                if (h.x >= 2.0f) m[c] |= (1u << (2 * j2));
                if (h.y >= 2.0f) m[c] |= (1u << (2 * j2 + 1));
            }
        }

        // ---- gate-1 only -> dense flags ----
        bool dense[RPL];
#pragma unroll
        for (int c = 0; c < RPL; ++c)
            dense[c] = m[c] && ((float)__popc(m[c]) * mxmax >= 1.998f);

        // ---- cooperative dense path (verbatim R11/R12, verified) ----
        if (__any(dense[0] || dense[1])) {
            // preload W2 row j=lane&31 into regs (L1/L2-hot)
            v4f w2r[8];
            {
                const v4f* wr = (const v4f*)(W2 + (lane & 31) * 32);
#pragma unroll
                for (int e = 0; e < 8; ++e) w2r[e] = wr[e];
            }
            const float* w2f = (const float*)w2r;

#pragma unroll
            for (int c = 0; c < RPL; ++c) {
                unsigned long long dmask = __ballot(dense[c]);
                while (dmask) {
                    const int L = (int)__ffsll(dmask) - 1;
                    dmask &= dmask - 1;
                    const unsigned mrow = __shfl(m[c], L);   // uniform bcast

                    // h2[j] for j=lane (lanes 0..31), ascending i,
                    // predicated +0.0 identity == verified skip form
                    float h2 = 0.0f;
#pragma unroll
                    for (int i = 0; i < 32; ++i)
                        h2 += ((mrow >> i) & 1u) ? w2f[i] : 0.0f;
                    const unsigned m2 =
                        (unsigned)__ballot(lane < 32 && h2 >= 2.0f);

                    if (m2) {   // rare
                        float g3 = 0.0f;
                        if (lane < 16) {
                            const float* w3r = W3 + lane * 32;
#pragma unroll
                            for (int i = 0; i < 32; ++i)
                                g3 += ((m2 >> i) & 1u) ? w3r[i] : 0.0f;
                        }
                        const unsigned m3 =
                            (unsigned)__ballot(lane < 16 && g3 >= 2.0f);
                        if (m3) {
                            float g4 = 0.0f;
                            if (lane < 10) {
                                const float* w4r = W4 + lane * 16;
#pragma unroll
                                for (int i = 0; i < 16; ++i)
                                    g4 += ((m3 >> i) & 1u) ? w4r[i] : 0.0f;
                            }
                            __builtin_amdgcn_s_waitcnt(0);  // order vs zero-burst
                            if (lane < 10)
                                out[(wt0 + (long)L * RPL + c) * 10 + lane] =
                                    (g4 >= 2.0f) ? 1.0f : 0.0f;
                        }
                    }
                }
            }
        }
    } else {
        // ---- tail wave (not hit at B=2^21; correctness-general, serial) ----
        for (int c = 0; c < RPL; ++c) {
            const long r = wt0 + (long)lane * RPL + c;
            if (r >= B) continue;
            float xr[5];
#pragma unroll
            for (int k = 0; k < 5; ++k) xr[k] = x[r * 5 + k];
            unsigned mc = 0u;
#pragma unroll
            for (int j = 0; j < 32; ++j) {
                const float* w = W1 + j * 5;
                float h = xr[0] * w[0];
                h += xr[1] * w[1];
                h += xr[2] * w[2];
                h += xr[3] * w[3];
                h += xr[4] * w[4];
                if (h >= 2.0f) mc |= (1u << j);
            }
            float o[10];
#pragma unroll
            for (int j = 0; j < 10; ++j) o[j] = 0.0f;
            if (mc && ((float)__popc(mc) * mxmax >= 1.998f)) {
                // serial dense: VERBATIM verified ascending set-bit order
                float h2[32];
#pragma unroll
                for (int j = 0; j < 32; ++j) h2[j] = 0.0f;
                unsigned mm = mc;
                while (mm) {
                    const int i = __ffs(mm) - 1;
                    mm &= mm - 1;
                    const float* colp = W2 + i;   // W2^T[i][j] == W2[j*32+i]
#pragma unroll
                    for (int j = 0; j < 32; ++j) h2[j] += colp[j * 32];
                }
                unsigned m2 = 0u;
#pragma unroll
                for (int j = 0; j < 32; ++j)
                    if (h2[j] >= 2.0f) m2 |= (1u << j);
                if (m2) {
                    unsigned m3 = 0u;
#pragma unroll
                    for (int j = 0; j < 16; ++j) {
                        float gg = 0.0f;
#pragma unroll
                        for (int i = 0; i < 32; ++i)
                            if ((m2 >> i) & 1u) gg += W3[j * 32 + i];
                        if (gg >= 2.0f) m3 |= (1u << j);
                    }
#pragma unroll
                    for (int j = 0; j < 10; ++j) {
                        float gg = 0.0f;
#pragma unroll
                        for (int i = 0; i < 16; ++i)
                            if ((m3 >> i) & 1u) gg += W4[j * 16 + i];
                        o[j] = (gg >= 2.0f) ? 1.0f : 0.0f;
                    }
                }
            }
#pragma unroll
            for (int j = 0; j < 10; ++j) out[r * 10 + j] = o[j];
        }
    }
}

extern "C" void kernel_launch(void* const* d_in, const int* in_sizes, int n_in,
                              void* d_out, int out_size, void* d_ws, size_t ws_size,
                              hipStream_t stream) {
    const float* x  = (const float*)d_in[0];
    const float* W1 = (const float*)d_in[1];
    const float* W2 = (const float*)d_in[2];
    const float* W3 = (const float*)d_in[3];
    const float* W4 = (const float*)d_in[4];
    float* out = (float*)d_out;

    int B = in_sizes[0] / 5;
    int grid = (B + RPB - 1) / RPB;
    snn_one<<<grid, TPB, 0, stream>>>(x, W1, W2, W3, W4, out, B);
}

// Round 10
// 135.287 us; speedup vs baseline: 1.0705x; 1.0705x over previous
//
#include <hip/hip_runtime.h>

// SNN forward — R14: R12 (best, kernel <50us) + shuffle-tree colmax from R13.
//
// R13 post-mortem: removing gate-2 sent ~59% of waves (vs ~9%) into the
// cooperative dense block; its per-event cost x 6.5 frequency made the
// kernel VALU-bound (69%) and slower (54us vs <50). Gate-2's FILTER is
// worth keeping; only its infra (32 strided loads + 31-deep dependent fmax
// chain + LDS round-trip) was bad. R14 = R12 with that infra replaced:
//
//  colmax via coalesced loads + shuffle tree (exact same values):
//   - v4f element k of W2 = row k>>3, cols 4(k&7)..+3. Lane l's loads
//     {l, 64+l, 128+l, 192+l} = rows {r,r+8,r+16,r+24} (r=l>>3), fixed
//     col-group l&7. Component-wise max + shfl_xor over {8,16,32} (varies
//     r over 0..7) = colmax of the lane's 4 cols. Lanes<8 write smx[32].
//   - 3 more max+shfl steps over l&7 -> mxmax (all lanes).
//   - fmax is exactly associative/commutative -> values identical to the
//     R12 serial scan -> gate decisions identical -> absmax 0.0 preserved.
//
// Everything else VERBATIM R12 (verified absmax 0.0): packed-v2f layer-1
// (R6/R7/R12), early zero-burst, gate-1 popc bound, gate-2 S-loop
// (fp sum err <= 31*2^-24*Sum|terms| ~ 4e-5 << margin), cooperative dense
// path (predicated +0.0 identity, ascending i), wave-private LDS x-stage,
// no barriers.

typedef float v4f __attribute__((ext_vector_type(4)));
typedef float v2f __attribute__((ext_vector_type(2)));

#define TPB 256
#define RPL 2                  // rows per lane
#define TROWS (64 * RPL)       // 128 rows per wave
#define RPB (TPB * RPL)        // 512 rows per block

__global__ __launch_bounds__(TPB) void snn_one(
    const float* __restrict__ x,
    const float* __restrict__ W1,   // [32,5]
    const float* __restrict__ W2,   // [32,32]
    const float* __restrict__ W3,   // [16,32]
    const float* __restrict__ W4,   // [10,16]
    float* __restrict__ out,        // [B,10]
    int B)
{
    __shared__ __align__(16) float xsh[4][TROWS * 5];   // 10KB: wave-private x
    __shared__ __align__(16) float smxl[4][32];         // per-wave colmax

    const int t = threadIdx.x;
    const int wv = t >> 6, lane = t & 63;
    float* sb = xsh[wv];
    const long wt0 = (long)blockIdx.x * RPB + (long)wv * TROWS;
    if (wt0 >= B) return;

    const bool full = (wt0 + TROWS <= B);

    // ---- issue this wave's x loads FIRST ----
    v4f g0, g1, g2;
    if (full) {
        const v4f* xg = (const v4f*)(x + wt0 * 5);
        g0 = xg[lane];
        g1 = xg[64 + lane];
        if (lane < 32) g2 = xg[128 + lane];   // 160 v4f total
    }

    // ---- W2 coalesced loads for colmax (4 v4f/lane = all 1024 floats) ----
    v4f wm0, wm1, wm2, wm3;
    {
        const v4f* w2g = (const v4f*)W2;
        wm0 = w2g[lane];
        wm1 = w2g[64 + lane];
        wm2 = w2g[128 + lane];
        wm3 = w2g[192 + lane];
    }

    // ---- EARLY coalesced zero-burst: drain overlaps compute below ----
    if (full) {
        v4f z = {0.0f, 0.0f, 0.0f, 0.0f};
        v4f* og = (v4f*)(out + wt0 * 10);
#pragma unroll
        for (int e = 0; e < 5; ++e) og[e * 64 + lane] = z;
    }

    // ---- shuffle-tree colmax + mxmax (exact; no strided loads/chains) ----
    float mxmax;
    {
        v4f vm;
        vm.x = fmaxf(fmaxf(wm0.x, wm1.x), fmaxf(wm2.x, wm3.x));
        vm.y = fmaxf(fmaxf(wm0.y, wm1.y), fmaxf(wm2.y, wm3.y));
        vm.z = fmaxf(fmaxf(wm0.z, wm1.z), fmaxf(wm2.z, wm3.z));
        vm.w = fmaxf(fmaxf(wm0.w, wm1.w), fmaxf(wm2.w, wm3.w));
#pragma unroll
        for (int off = 8; off <= 32; off <<= 1) {
            vm.x = fmaxf(vm.x, __shfl_xor(vm.x, off));
            vm.y = fmaxf(vm.y, __shfl_xor(vm.y, off));
            vm.z = fmaxf(vm.z, __shfl_xor(vm.z, off));
            vm.w = fmaxf(vm.w, __shfl_xor(vm.w, off));
        }
        // lane holds colmax for cols 4*(lane&7)..+3 (replicated over lane>>3)
        if (lane < 8) *(v4f*)(&smxl[wv][4 * lane]) = vm;
        float mx = fmaxf(fmaxf(vm.x, vm.y), fmaxf(vm.z, vm.w));
#pragma unroll
        for (int off = 1; off <= 4; off <<= 1)
            mx = fmaxf(mx, __shfl_xor(mx, off));
        mxmax = mx;
    }
    const float* __restrict__ smx = smxl[wv];

    if (full) {
        // ---- stage x -> wave-private LDS, read back own 2 rows ----
        v4f* s4 = (v4f*)sb;
        s4[lane] = g0;
        s4[64 + lane] = g1;
        if (lane < 32) s4[128 + lane] = g2;

        v2f xp[5];
        {
            const v2f* sx = (const v2f*)(sb + lane * 10);
#pragma unroll
            for (int e = 0; e < 5; ++e) xp[e] = sx[e];
        }
        const float* xf = (const float*)xp;

        // ---- layer 1: packed v2f, j2-outer (R6/R7/R12-verified form) ----
        unsigned m[RPL] = {0u, 0u};
#pragma unroll
        for (int j2 = 0; j2 < 16; ++j2) {
            const float* wA = W1 + (2 * j2) * 5;
            const float* wB = W1 + (2 * j2 + 1) * 5;
            const v2f w0 = {wA[0], wB[0]};
            const v2f w1 = {wA[1], wB[1]};
            const v2f w2 = {wA[2], wB[2]};
            const v2f w3 = {wA[3], wB[3]};
            const v2f w4 = {wA[4], wB[4]};
#pragma unroll
            for (int c = 0; c < RPL; ++c) {
                v2f h = xf[c * 5 + 0] * w0;   // exact per-neuron chain order
                h += xf[c * 5 + 1] * w1;
                h += xf[c * 5 + 2] * w2;
                h += xf[c * 5 + 3] * w3;
                h += xf[c * 5 + 4] * w4;
                if (h.x >= 2.0f) m[c] |= (1u << (2 * j2));
                if (h.y >= 2.0f) m[c] |= (1u << (2 * j2 + 1));
            }
        }

        // ---- gates: gate-1 popc bound, then gate-2 S-loop (R12 form) ----
        bool dense[RPL];
#pragma unroll
        for (int c = 0; c < RPL; ++c) {
            dense[c] = false;
            const unsigned mc = m[c];
            if (mc && ((float)__popc(mc) * mxmax >= 1.998f)) {
                float S = 0.0f;
                unsigned mm = mc;
                while (mm) { int i = __ffs(mm) - 1; mm &= mm - 1; S += smx[i]; }
                dense[c] = (S >= 1.998f);
            }
        }

        // ---- cooperative dense path (verbatim R11/R12, verified) ----
        if (__any(dense[0] || dense[1])) {
            // preload W2 row j=lane&31 into regs (L1/L2-hot)
            v4f w2r[8];
            {
                const v4f* wr = (const v4f*)(W2 + (lane & 31) * 32);
#pragma unroll
                for (int e = 0; e < 8; ++e) w2r[e] = wr[e];
            }
            const float* w2f = (const float*)w2r;

#pragma unroll
            for (int c = 0; c < RPL; ++c) {
                unsigned long long dmask = __ballot(dense[c]);
                while (dmask) {
                    const int L = (int)__ffsll(dmask) - 1;
                    dmask &= dmask - 1;
                    const unsigned mrow = __shfl(m[c], L);   // uniform bcast

                    // h2[j] for j=lane (lanes 0..31), ascending i,
                    // predicated +0.0 identity == verified skip form
                    float h2 = 0.0f;
#pragma unroll
                    for (int i = 0; i < 32; ++i)
                        h2 += ((mrow >> i) & 1u) ? w2f[i] : 0.0f;
                    const unsigned m2 =
                        (unsigned)__ballot(lane < 32 && h2 >= 2.0f);

                    if (m2) {   // ultra-rare
                        float g3 = 0.0f;
                        if (lane < 16) {
                            const float* w3r = W3 + lane * 32;
#pragma unroll
                            for (int i = 0; i < 32; ++i)
                                g3 += ((m2 >> i) & 1u) ? w3r[i] : 0.0f;
                        }
                        const unsigned m3 =
                            (unsigned)__ballot(lane < 16 && g3 >= 2.0f);
                        if (m3) {
                            float g4 = 0.0f;
                            if (lane < 10) {
                                const float* w4r = W4 + lane * 16;
#pragma unroll
                                for (int i = 0; i < 16; ++i)
                                    g4 += ((m3 >> i) & 1u) ? w4r[i] : 0.0f;
                            }
                            __builtin_amdgcn_s_waitcnt(0);  // order vs zero-burst
                            if (lane < 10)
                                out[(wt0 + (long)L * RPL + c) * 10 + lane] =
                                    (g4 >= 2.0f) ? 1.0f : 0.0f;
                        }
                    }
                }
            }
        }
    } else {
        // ---- tail wave (not hit at B=2^21; correctness-general, serial) ----
        for (int c = 0; c < RPL; ++c) {
            const long r = wt0 + (long)lane * RPL + c;
            if (r >= B) continue;
            float xr[5];
#pragma unroll
            for (int k = 0; k < 5; ++k) xr[k] = x[r * 5 + k];
            unsigned mc = 0u;
#pragma unroll
            for (int j = 0; j < 32; ++j) {
                const float* w = W1 + j * 5;
                float h = xr[0] * w[0];
                h += xr[1] * w[1];
                h += xr[2] * w[2];
                h += xr[3] * w[3];
                h += xr[4] * w[4];
                if (h >= 2.0f) mc |= (1u << j);
            }
            float o[10];
#pragma unroll
            for (int j = 0; j < 10; ++j) o[j] = 0.0f;
            if (mc && ((float)__popc(mc) * mxmax >= 1.998f)) {
                float S = 0.0f;
                unsigned mm = mc;
                while (mm) { int i = __ffs(mm) - 1; mm &= mm - 1; S += smx[i]; }
                if (S >= 1.998f) {
                    // serial dense: VERBATIM verified ascending set-bit order
                    float h2[32];
#pragma unroll
                    for (int j = 0; j < 32; ++j) h2[j] = 0.0f;
                    mm = mc;
                    while (mm) {
                        const int i = __ffs(mm) - 1;
                        mm &= mm - 1;
                        const float* colp = W2 + i;   // W2^T[i][j] == W2[j*32+i]
#pragma unroll
                        for (int j = 0; j < 32; ++j) h2[j] += colp[j * 32];
                    }
                    unsigned m2 = 0u;
#pragma unroll
                    for (int j = 0; j < 32; ++j)
                        if (h2[j] >= 2.0f) m2 |= (1u << j);
                    if (m2) {
                        unsigned m3 = 0u;
#pragma unroll
                        for (int j = 0; j < 16; ++j) {
                            float gg = 0.0f;
#pragma unroll
                            for (int i = 0; i < 32; ++i)
                                if ((m2 >> i) & 1u) gg += W3[j * 32 + i];
                            if (gg >= 2.0f) m3 |= (1u << j);
                        }
#pragma unroll
                        for (int j = 0; j < 10; ++j) {
                            float gg = 0.0f;
#pragma unroll
                            for (int i = 0; i < 16; ++i)
                                if ((m3 >> i) & 1u) gg += W4[j * 16 + i];
                            o[j] = (gg >= 2.0f) ? 1.0f : 0.0f;
                        }
                    }
                }
            }
#pragma unroll
            for (int j = 0; j < 10; ++j) out[r * 10 + j] = o[j];
        }
    }
}

extern "C" void kernel_launch(void* const* d_in, const int* in_sizes, int n_in,
                              void* d_out, int out_size, void* d_ws, size_t ws_size,
                              hipStream_t stream) {
    const float* x  = (const float*)d_in[0];
    const float* W1 = (const float*)d_in[1];
    const float* W2 = (const float*)d_in[2];
    const float* W3 = (const float*)d_in[3];
    const float* W4 = (const float*)d_in[4];
    float* out = (float*)d_out;

    int B = in_sizes[0] / 5;
    int grid = (B + RPB - 1) / RPB;
    snn_one<<<grid, TPB, 0, stream>>>(x, W1, W2, W3, W4, out, B);
}